// Round 12
// baseline (477.785 us; speedup 1.0000x reference)
//
#include <hip/hip_runtime.h>

typedef short bf16x8 __attribute__((ext_vector_type(8)));
typedef float f32x4 __attribute__((ext_vector_type(4)));

#define AS1 __attribute__((address_space(1)))
#define AS3 __attribute__((address_space(3)))

// async global->LDS, 16B per lane. LDS dest is wave-uniform base + lane*16.
__device__ __forceinline__ void async16(const void* g, void* l) {
    __builtin_amdgcn_global_load_lds((AS1 unsigned*)(unsigned long long)g,
                                     (AS3 unsigned*)l, 16, 0, 0);
}

__device__ __forceinline__ unsigned short f2bf(float f) {
    unsigned u = __builtin_bit_cast(unsigned, f);
    u += 0x7fffu + ((u >> 16) & 1u);   // RNE
    return (unsigned short)(u >> 16);
}
__device__ __forceinline__ float bf2f(unsigned short s) {
    unsigned u = ((unsigned)s) << 16;
    return __builtin_bit_cast(float, u);
}

// ---------------- LayerNorm + bf16 cast: one wave per row of 512 ----------------
__global__ __launch_bounds__(256) void ln_bf16_kernel(
    const float* __restrict__ x, const float* __restrict__ gamma,
    const float* __restrict__ beta, unsigned short* __restrict__ xn, int nrows)
{
    int row = blockIdx.x * 4 + (threadIdx.x >> 6);
    int lane = threadIdx.x & 63;
    if (row >= nrows) return;
    const float4* xr = (const float4*)(x + (size_t)row * 512);
    float4 a = xr[lane], b = xr[lane + 64];
    float s = a.x + a.y + a.z + a.w + b.x + b.y + b.z + b.w;
    #pragma unroll
    for (int m = 1; m < 64; m <<= 1) s += __shfl_xor(s, m);
    float mu = s * (1.0f / 512.0f);
    float dx[8] = {a.x - mu, a.y - mu, a.z - mu, a.w - mu,
                   b.x - mu, b.y - mu, b.z - mu, b.w - mu};
    float ss = 0.f;
    #pragma unroll
    for (int i = 0; i < 8; ++i) ss += dx[i] * dx[i];
    #pragma unroll
    for (int m = 1; m < 64; m <<= 1) ss += __shfl_xor(ss, m);
    float rstd = rsqrtf(ss * (1.0f / 512.0f) + 1e-5f);
    const float4* gp = (const float4*)gamma;
    const float4* bp = (const float4*)beta;
    float4 g0 = gp[lane], g1 = gp[lane + 64], b0 = bp[lane], b1 = bp[lane + 64];
    float y[8];
    y[0] = dx[0] * rstd * g0.x + b0.x; y[1] = dx[1] * rstd * g0.y + b0.y;
    y[2] = dx[2] * rstd * g0.z + b0.z; y[3] = dx[3] * rstd * g0.w + b0.w;
    y[4] = dx[4] * rstd * g1.x + b1.x; y[5] = dx[5] * rstd * g1.y + b1.y;
    y[6] = dx[6] * rstd * g1.z + b1.z; y[7] = dx[7] * rstd * g1.w + b1.w;
    ushort4* orow = (ushort4*)(xn + (size_t)row * 512);
    orow[lane]      = make_ushort4(f2bf(y[0]), f2bf(y[1]), f2bf(y[2]), f2bf(y[3]));
    orow[lane + 64] = make_ushort4(f2bf(y[4]), f2bf(y[5]), f2bf(y[6]), f2bf(y[7]));
}

// ---- fp32 [R][C] -> bf16 transposed [C][R], BOTH weights in one launch ----
__global__ __launch_bounds__(256) void transpose_w2(
    const float* __restrict__ wqkv, const float* __restrict__ wproj,
    unsigned short* __restrict__ wqkvT, unsigned short* __restrict__ wprojT)
{
    __shared__ float tile[64][65];
    const int R = 512;
    int by = blockIdx.y;
    const float* in;
    unsigned short* outT;
    int Cd, c0;
    if (by < 24) { in = wqkv;  outT = wqkvT;  Cd = 1536; c0 = by * 64; }
    else         { in = wproj; outT = wprojT; Cd = 512;  c0 = (by - 24) * 64; }
    int r0 = blockIdx.x * 64;
    int lr = threadIdx.x >> 6, lc = threadIdx.x & 63;
    #pragma unroll
    for (int i = 0; i < 16; ++i) {
        int r = i * 4 + lr;
        tile[r][lc] = in[(size_t)(r0 + r) * Cd + c0 + lc];
    }
    __syncthreads();
    #pragma unroll
    for (int i = 0; i < 16; ++i) {
        int r = i * 4 + lr;
        outT[(size_t)(c0 + r) * R + r0 + lc] = f2bf(tile[lc][r]);
    }
}

// -------- merged QKV GEMM: C[16384,1536] = xn[16384,512] * WqkvT[1536,512]^T --------
__global__ __launch_bounds__(256) void gemm_qkv(
    const unsigned short* __restrict__ A, const unsigned short* __restrict__ Bt,
    unsigned short* __restrict__ qkOut, unsigned short* __restrict__ vtp)
{
    __shared__ unsigned short As[128 * 64];
    __shared__ unsigned short Bs[128 * 64];
    const int tid = threadIdx.x;
    const int w = tid >> 6, lane = tid & 63, quad = lane >> 4, l15 = lane & 15;
    const int wm = w >> 1, wn = w & 1;
    const size_t m0 = (size_t)blockIdx.x * 128, n0 = (size_t)blockIdx.y * 128;
    f32x4 zero = {0.f, 0.f, 0.f, 0.f};
    f32x4 acc[4][4];
    #pragma unroll
    for (int i = 0; i < 4; ++i)
        #pragma unroll
        for (int j = 0; j < 4; ++j) acc[i][j] = zero;

    for (int k0 = 0; k0 < 512; k0 += 64) {
        __syncthreads();
        #pragma unroll
        for (int r = 0; r < 4; ++r) {
            int s = r * 256 + w * 64 + lane;
            int row = s >> 3, x = s & 7, g = x ^ (row & 7);
            async16(A + (m0 + row) * 512 + k0 + g * 8,
                    (char*)As + (size_t)(r * 256 + w * 64) * 16);
        }
        #pragma unroll
        for (int r = 0; r < 4; ++r) {
            int s = r * 256 + w * 64 + lane;
            int row = s >> 3, x = s & 7, g = x ^ (row & 7);
            async16(Bt + (n0 + row) * 512 + k0 + g * 8,
                    (char*)Bs + (size_t)(r * 256 + w * 64) * 16);
        }
        __syncthreads();
        #pragma unroll
        for (int ks = 0; ks < 2; ++ks) {
            bf16x8 af[4], bf[4];
            int cc = ks * 4 + quad;
            #pragma unroll
            for (int mt = 0; mt < 4; ++mt) {
                int row = wm * 64 + mt * 16 + l15;
                int x = cc ^ (row & 7);
                af[mt] = *(const bf16x8*)(As + row * 64 + x * 8);
            }
            #pragma unroll
            for (int nt = 0; nt < 4; ++nt) {
                int row = wn * 64 + nt * 16 + l15;
                int x = cc ^ (row & 7);
                bf[nt] = *(const bf16x8*)(Bs + row * 64 + x * 8);
            }
            #pragma unroll
            for (int mt = 0; mt < 4; ++mt)
                #pragma unroll
                for (int nt = 0; nt < 4; ++nt)
                    acc[mt][nt] = __builtin_amdgcn_mfma_f32_16x16x32_bf16(
                        af[mt], bf[nt], acc[mt][nt], 0, 0, 0);
        }
    }
    if (n0 < 1024) {
        #pragma unroll
        for (int mt = 0; mt < 4; ++mt)
            #pragma unroll
            for (int nt = 0; nt < 4; ++nt)
                #pragma unroll
                for (int r = 0; r < 4; ++r) {
                    size_t grow = m0 + wm * 64 + mt * 16 + quad * 4 + r;
                    size_t gcol = n0 + wn * 64 + nt * 16 + l15;
                    qkOut[grow * 1024 + gcol] = f2bf(acc[mt][nt][r]);
                }
    } else {
        const int b = (int)(m0 >> 12);
        const int tb = (int)(m0 & 4095);
        #pragma unroll
        for (int mt = 0; mt < 4; ++mt)
            #pragma unroll
            for (int nt = 0; nt < 4; ++nt)
                #pragma unroll
                for (int r = 0; r < 4; ++r) {
                    int t = tb + wm * 64 + mt * 16 + quad * 4 + r;
                    int vcol = (int)(n0 - 1024) + wn * 64 + nt * 16 + l15;
                    int jt = t >> 5;
                    int x = (t >> 3) & 3;
                    vtp[(size_t)(b * 128 + jt) * 16384
                        + (size_t)(vcol * 4 + x) * 8 + (t & 7)] =
                        f2bf(acc[mt][nt][r]);
                }
    }
}

// ---- zero the fp32 O-accumulator (accLo/accHi) + row-sum accumulator lacc ----
__global__ __launch_bounds__(256) void zero_kernel(
    float4* __restrict__ accLo, float4* __restrict__ accHi,
    float4* __restrict__ lacc)
{
    const float4 z = {0.f, 0.f, 0.f, 0.f};
    size_t stride = (size_t)gridDim.x * 256;
    for (size_t i = blockIdx.x * 256 + threadIdx.x; i < 1048576; i += stride) {
        accLo[i] = z;
        accHi[i] = z;
    }
    for (size_t i = blockIdx.x * 256 + threadIdx.x; i < 4096; i += stride)
        lacc[i] = z;
}

// ---------------- Flash attention v18: balanced quarter-jobs + atomic fp32 O ----------------
// v15 loop body (QBLK=64, KVBLK=32, dbuf K in LDS, no V staging, d-split PV,
// setprio). SCHEDULE FIX: old pairing left a CU's long block running SOLO for
// ~half its tiles (latency-bound kernel + avg |63-2a| tile imbalance within a
// CU). Now: each row-block q's 2q+2 key-tiles split into 4 quarter-ranges
// (each <=32); block i in [0,512) runs TWO sequential sub-jobs -- quarter j2 of
// row a, then quarter j2+2 of row 63-a -- totaling 32-33 tiles for EVERY block.
// Any two co-resident blocks are equal -> no solo tail, placement-robust.
// Partials (4 writers per row) accumulate via fp32 atomicAdd into acc
// (rows<8192 in accLo, else accHi) + lacc row sums; gemm_proj normalizes.
__global__ __launch_bounds__(256, 2) void attn_kernel(
    const unsigned short* __restrict__ qk,    // [b*4096+t][1024] : Q | K
    const unsigned short* __restrict__ vtp,   // UNSWIZZLED panels [b][jt][2048 chunks]
    float* __restrict__ accLo, float* __restrict__ accHi,
    float* __restrict__ lacc)
{
    __shared__ unsigned short Ks[2][32 * 512];   // 2x32 KB, source-permuted chunks
    __shared__ unsigned short Ps[64 * 40];       // 5 KB P exchange, stride-40 pad

    const int i = blockIdx.x;
    const int a = i & 63, b = (i >> 6) & 3, j2 = i >> 8;   // j2 in {0,1}

    const int tid = threadIdx.x, w = tid >> 6, lane = tid & 63;
    const int quad = lane >> 4, l15 = lane & 15;
    const float scale = 0.04419417382415922f;  // 1/sqrt(512)
    f32x4 zero = {0.f, 0.f, 0.f, 0.f};

    const unsigned short* kbase = qk + (size_t)(b * 4096) * 1024 + 512;
    const unsigned short* vbase = vtp + (size_t)(b * 128) * 16384;
    float* accB = (b & 2) ? accHi : accLo;

    const int gE = (lane & ~7) | ((lane ^ w) & 7);
    const int gO = (lane & ~7) | ((lane ^ (w + 4)) & 7);
    const size_t kOffE = (size_t)w * 1024 + (size_t)gE * 8;
    const size_t kOffO = (size_t)(w + 4) * 1024 + (size_t)gO * 8;
    const size_t vLane = (size_t)w * 4096 + (size_t)l15 * 32 + (size_t)quad * 8;

    #define STAGE_K(BUF, T)                                                      \
    {                                                                            \
        const unsigned short* kg = kbase + (size_t)(T) * 32768;                  \
        _Pragma("unroll")                                                        \
        for (int rr = 0; rr < 4; ++rr) {                                         \
            async16(kg + (size_t)(2 * rr) * 4096 + kOffE,                        \
                    (char*)(&Ks[BUF][0]) + (size_t)((2 * rr) * 256 + w * 64) * 16);\
            async16(kg + (size_t)(2 * rr) * 4096 + kOffO,                        \
                    (char*)(&Ks[BUF][0]) + (size_t)((2 * rr + 1) * 256 + w * 64) * 16);\
        }                                                                        \
    }

    #pragma unroll 1
    for (int s = 0; s < 2; ++s) {
        const int q = s ? (63 - a) : a;
        const int j = s ? (j2 + 2) : j2;
        const int T2 = 2 * q + 2;
        const int t0 = (j * T2) >> 2;
        const int t1 = ((j + 1) * T2) >> 2;
        if (t0 >= t1) continue;               // empty quarter (block-uniform)

        // Q fragments for this row-block
        bf16x8 qf[16];
        {
            const unsigned short* qb =
                qk + (size_t)(b * 4096 + q * 64 + w * 16 + l15) * 1024;
            #pragma unroll
            for (int ks = 0; ks < 16; ++ks)
                qf[ks] = *(const bf16x8*)(qb + ks * 32 + quad * 8);
        }
        f32x4 o[4][8];
        #pragma unroll
        for (int ii = 0; ii < 4; ++ii)
            #pragma unroll
            for (int d = 0; d < 8; ++d) o[ii][d] = zero;
        float li[4] = {0.f, 0.f, 0.f, 0.f};

        STAGE_K(0, t0);
        __syncthreads();
        int cur = 0;

        #pragma unroll 1
        for (int jt = t0; jt < t1; ++jt) {
            if (jt + 1 < t1) STAGE_K(cur ^ 1, jt + 1);

            f32x4 sa[2];
            sa[0] = zero; sa[1] = zero;
            __builtin_amdgcn_s_setprio(1);
            #pragma unroll
            for (int ks = 0; ks < 16; ++ks) {
                int cc = ks * 4 + quad;
                #pragma unroll
                for (int nt = 0; nt < 2; ++nt) {
                    int jr = nt * 16 + l15;
                    int xg = (cc & ~7) | ((cc ^ jr) & 7);
                    bf16x8 kf = *(const bf16x8*)(&Ks[cur][jr * 512 + xg * 8]);
                    sa[nt] = __builtin_amdgcn_mfma_f32_16x16x32_bf16(
                        qf[ks], kf, sa[nt], 0, 0, 0);
                }
            }
            __builtin_amdgcn_s_setprio(0);
            const int trow = q * 64 + w * 16 + quad * 4;
            #pragma unroll
            for (int r = 0; r < 4; ++r) {
                #pragma unroll
                for (int nt = 0; nt < 2; ++nt) {
                    int col = jt * 32 + nt * 16 + l15;
                    float sv = sa[nt][r] * scale;
                    float pv = __expf(fminf(sv, 60.f));
                    if (col > trow + r) pv = 0.f;
                    li[r] += pv;
                    Ps[(w * 16 + quad * 4 + r) * 40 + nt * 16 + l15] = f2bf(pv);
                }
            }
            asm volatile("s_waitcnt lgkmcnt(0)" ::: "memory");
            __builtin_amdgcn_s_barrier();

            const unsigned short* vt = vbase + (size_t)jt * 16384 + vLane;
            bf16x8 vfr[8];
            #pragma unroll
            for (int ii = 0; ii < 8; ++ii)
                vfr[ii] = *(const bf16x8*)(vt + (size_t)ii * 512);
            __builtin_amdgcn_s_setprio(1);
            #pragma unroll
            for (int qi = 0; qi < 4; ++qi) {
                bf16x8 pa = *(const bf16x8*)(Ps + (qi * 16 + l15) * 40 + quad * 8);
                #pragma unroll
                for (int ii = 0; ii < 8; ++ii)
                    o[qi][ii] = __builtin_amdgcn_mfma_f32_16x16x32_bf16(
                        pa, vfr[ii], o[qi][ii], 0, 0, 0);
            }
            __builtin_amdgcn_s_setprio(0);
            __syncthreads();
            cur ^= 1;
        }

        // epilogue: atomic row-sum + atomic fp32 O accumulation
        #pragma unroll
        for (int r = 0; r < 4; ++r) {
            float t = li[r];
            t += __shfl_xor(t, 1);
            t += __shfl_xor(t, 2);
            t += __shfl_xor(t, 4);
            t += __shfl_xor(t, 8);
            if (l15 == 0)
                atomicAdd(&lacc[b * 4096 + q * 64 + w * 16 + quad * 4 + r], t);
        }
        float* ab = accB + (size_t)((b & 1) * 4096 + q * 64) * 512 + w * 128;
        #pragma unroll
        for (int qi = 0; qi < 4; ++qi)
            #pragma unroll
            for (int df = 0; df < 8; ++df)
                #pragma unroll
                for (int r = 0; r < 4; ++r)
                    atomicAdd(&ab[(size_t)(qi * 16 + quad * 4 + r) * 512
                                  + df * 16 + l15], o[qi][df][r]);
    }
    #undef STAGE_K
}

// ---- final projection GEMM with fused normalize: out = (acc/lacc) @ WprojT^T ----
__global__ __launch_bounds__(256) void gemm_proj(
    const float* __restrict__ accLo, const float* __restrict__ accHi,
    const float* __restrict__ lacc, const unsigned short* __restrict__ Bt,
    float* __restrict__ out)
{
    __shared__ unsigned short As[128 * 64];
    __shared__ unsigned short Bs[128 * 64];
    const int tid = threadIdx.x;
    const int w = tid >> 6, lane = tid & 63, quad = lane >> 4, l15 = lane & 15;
    const int wm = w >> 1, wn = w & 1;
    const size_t m0 = (size_t)blockIdx.x * 128, n0 = (size_t)blockIdx.y * 128;
    const float* accB = (m0 < 8192) ? accLo : accHi;
    f32x4 zero = {0.f, 0.f, 0.f, 0.f};
    f32x4 acc[4][4];
    #pragma unroll
    for (int i = 0; i < 4; ++i)
        #pragma unroll
        for (int j = 0; j < 4; ++j) acc[i][j] = zero;

    for (int k0 = 0; k0 < 512; k0 += 64) {
        __syncthreads();
        // A: normalize fp32 accumulator on the fly (same swizzled As layout)
        #pragma unroll
        for (int r = 0; r < 4; ++r) {
            int s = r * 256 + tid;
            int row = s >> 3, x = s & 7, g = x ^ (row & 7);
            size_t t = m0 + row;
            float inv = 1.0f / lacc[t];
            const float* src = accB + ((size_t)(t & 8191)) * 512 + k0 + g * 8;
            float4 fa = *(const float4*)(src);
            float4 fb = *(const float4*)(src + 4);
            bf16x8 v;
            v[0] = (short)f2bf(fa.x * inv); v[1] = (short)f2bf(fa.y * inv);
            v[2] = (short)f2bf(fa.z * inv); v[3] = (short)f2bf(fa.w * inv);
            v[4] = (short)f2bf(fb.x * inv); v[5] = (short)f2bf(fb.y * inv);
            v[6] = (short)f2bf(fb.z * inv); v[7] = (short)f2bf(fb.w * inv);
            *(bf16x8*)(As + (size_t)s * 8) = v;
        }
        // B: async copy
        #pragma unroll
        for (int r = 0; r < 4; ++r) {
            int s = r * 256 + w * 64 + lane;
            int row = s >> 3, x = s & 7, g = x ^ (row & 7);
            async16(Bt + (n0 + row) * 512 + k0 + g * 8,
                    (char*)Bs + (size_t)(r * 256 + w * 64) * 16);
        }
        __syncthreads();
        #pragma unroll
        for (int ks = 0; ks < 2; ++ks) {
            bf16x8 af[4], bf[4];
            int cc = ks * 4 + quad;
            #pragma unroll
            for (int mt = 0; mt < 4; ++mt) {
                int row = wm * 64 + mt * 16 + l15;
                int x = cc ^ (row & 7);
                af[mt] = *(const bf16x8*)(As + row * 64 + x * 8);
            }
            #pragma unroll
            for (int nt = 0; nt < 4; ++nt) {
                int row = wn * 64 + nt * 16 + l15;
                int x = cc ^ (row & 7);
                bf[nt] = *(const bf16x8*)(Bs + row * 64 + x * 8);
            }
            #pragma unroll
            for (int mt = 0; mt < 4; ++mt)
                #pragma unroll
                for (int nt = 0; nt < 4; ++nt)
                    acc[mt][nt] = __builtin_amdgcn_mfma_f32_16x16x32_bf16(
                        af[mt], bf[nt], acc[mt][nt], 0, 0, 0);
        }
    }
    #pragma unroll
    for (int mt = 0; mt < 4; ++mt)
        #pragma unroll
        for (int nt = 0; nt < 4; ++nt)
            #pragma unroll
            for (int r = 0; r < 4; ++r) {
                size_t grow = m0 + wm * 64 + mt * 16 + quad * 4 + r;
                size_t gcol = n0 + wn * 64 + nt * 16 + l15;
                out[grow * 512 + gcol] = acc[mt][nt][r];
            }
}

extern "C" void kernel_launch(void* const* d_in, const int* in_sizes, int n_in,
                              void* d_out, int out_size, void* d_ws, size_t ws_size,
                              hipStream_t stream)
{
    const float* x     = (const float*)d_in[0];
    // d_in[1] = causal mask (tril ones) — causality applied analytically, not read
    const float* gamma = (const float*)d_in[2];
    const float* beta  = (const float*)d_in[3];
    const float* Wqkv  = (const float*)d_in[4];
    const float* Wproj = (const float*)d_in[5];
    float* out = (float*)d_out;

    char* ws = (char*)d_ws;
    unsigned short* qk     = (unsigned short*)(ws);              // 16384x1024 bf16 (32 MB)
    float*          accLo  = (float*)(ws + 33554432);            // rows 0..8191 fp32 (16 MB)
    unsigned short* vtp    = (unsigned short*)(ws + 50331648);   // packed Vt (16 MB)
    unsigned short* xn     = (unsigned short*)(ws + 67108864);   // LN out (16 MB); accHi later
    unsigned short* wqkvT  = (unsigned short*)(ws + 83886080);   // 1536x512 bf16; lacc later
    unsigned short* wprojT = (unsigned short*)(ws + 85458944);   // 512x512 bf16
    float*          accHi  = (float*)xn;     // rows 8192..16383 (dead after gemm_qkv)
    float*          lacc   = (float*)wqkvT;  // 16384 fp32 (dead after gemm_qkv)

    ln_bf16_kernel<<<4096, 256, 0, stream>>>(x, gamma, beta, xn, 16384);
    transpose_w2<<<dim3(8, 32), 256, 0, stream>>>(Wqkv, Wproj, wqkvT, wprojT);
    // merged QKV projection: Q|K -> qk (ldc 1024), V -> vtp (direct scatter)
    gemm_qkv<<<dim3(128, 12), 256, 0, stream>>>(xn, wqkvT, qk, vtp);
    zero_kernel<<<1024, 256, 0, stream>>>((float4*)accLo, (float4*)accHi,
                                          (float4*)lacc);
    attn_kernel<<<512, 256, 0, stream>>>(qk, vtp, accLo, accHi, lacc);
    // final projection with fused normalize (reads acc, lacc directly)
    gemm_proj<<<dim3(128, 4), 256, 0, stream>>>(accLo, accHi, lacc, wprojT, out);
}

// Round 13
// 407.153 us; speedup vs baseline: 1.1735x; 1.1735x over previous
//
#include <hip/hip_runtime.h>

typedef short bf16x8 __attribute__((ext_vector_type(8)));
typedef float f32x4 __attribute__((ext_vector_type(4)));

#define AS1 __attribute__((address_space(1)))
#define AS3 __attribute__((address_space(3)))

// async global->LDS, 16B per lane. LDS dest is wave-uniform base + lane*16.
__device__ __forceinline__ void async16(const void* g, void* l) {
    __builtin_amdgcn_global_load_lds((AS1 unsigned*)(unsigned long long)g,
                                     (AS3 unsigned*)l, 16, 0, 0);
}

__device__ __forceinline__ unsigned short f2bf(float f) {
    unsigned u = __builtin_bit_cast(unsigned, f);
    u += 0x7fffu + ((u >> 16) & 1u);   // RNE
    return (unsigned short)(u >> 16);
}
__device__ __forceinline__ float bf2f(unsigned short s) {
    unsigned u = ((unsigned)s) << 16;
    return __builtin_bit_cast(float, u);
}

// ---------------- LayerNorm + bf16 cast: one wave per row of 512 ----------------
__global__ __launch_bounds__(256) void ln_bf16_kernel(
    const float* __restrict__ x, const float* __restrict__ gamma,
    const float* __restrict__ beta, unsigned short* __restrict__ xn, int nrows)
{
    int row = blockIdx.x * 4 + (threadIdx.x >> 6);
    int lane = threadIdx.x & 63;
    if (row >= nrows) return;
    const float4* xr = (const float4*)(x + (size_t)row * 512);
    float4 a = xr[lane], b = xr[lane + 64];
    float s = a.x + a.y + a.z + a.w + b.x + b.y + b.z + b.w;
    #pragma unroll
    for (int m = 1; m < 64; m <<= 1) s += __shfl_xor(s, m);
    float mu = s * (1.0f / 512.0f);
    float dx[8] = {a.x - mu, a.y - mu, a.z - mu, a.w - mu,
                   b.x - mu, b.y - mu, b.z - mu, b.w - mu};
    float ss = 0.f;
    #pragma unroll
    for (int i = 0; i < 8; ++i) ss += dx[i] * dx[i];
    #pragma unroll
    for (int m = 1; m < 64; m <<= 1) ss += __shfl_xor(ss, m);
    float rstd = rsqrtf(ss * (1.0f / 512.0f) + 1e-5f);
    const float4* gp = (const float4*)gamma;
    const float4* bp = (const float4*)beta;
    float4 g0 = gp[lane], g1 = gp[lane + 64], b0 = bp[lane], b1 = bp[lane + 64];
    float y[8];
    y[0] = dx[0] * rstd * g0.x + b0.x; y[1] = dx[1] * rstd * g0.y + b0.y;
    y[2] = dx[2] * rstd * g0.z + b0.z; y[3] = dx[3] * rstd * g0.w + b0.w;
    y[4] = dx[4] * rstd * g1.x + b1.x; y[5] = dx[5] * rstd * g1.y + b1.y;
    y[6] = dx[6] * rstd * g1.z + b1.z; y[7] = dx[7] * rstd * g1.w + b1.w;
    ushort4* orow = (ushort4*)(xn + (size_t)row * 512);
    orow[lane]      = make_ushort4(f2bf(y[0]), f2bf(y[1]), f2bf(y[2]), f2bf(y[3]));
    orow[lane + 64] = make_ushort4(f2bf(y[4]), f2bf(y[5]), f2bf(y[6]), f2bf(y[7]));
}

// ---- fp32 [R][C] -> bf16 transposed [C][R], BOTH weights in one launch ----
__global__ __launch_bounds__(256) void transpose_w2(
    const float* __restrict__ wqkv, const float* __restrict__ wproj,
    unsigned short* __restrict__ wqkvT, unsigned short* __restrict__ wprojT)
{
    __shared__ float tile[64][65];
    const int R = 512;
    int by = blockIdx.y;
    const float* in;
    unsigned short* outT;
    int Cd, c0;
    if (by < 24) { in = wqkv;  outT = wqkvT;  Cd = 1536; c0 = by * 64; }
    else         { in = wproj; outT = wprojT; Cd = 512;  c0 = (by - 24) * 64; }
    int r0 = blockIdx.x * 64;
    int lr = threadIdx.x >> 6, lc = threadIdx.x & 63;
    #pragma unroll
    for (int i = 0; i < 16; ++i) {
        int r = i * 4 + lr;
        tile[r][lc] = in[(size_t)(r0 + r) * Cd + c0 + lc];
    }
    __syncthreads();
    #pragma unroll
    for (int i = 0; i < 16; ++i) {
        int r = i * 4 + lr;
        outT[(size_t)(c0 + r) * R + r0 + lc] = f2bf(tile[lc][r]);
    }
}

// -------- merged QKV GEMM: C[16384,1536] = xn[16384,512] * WqkvT[1536,512]^T --------
__global__ __launch_bounds__(256) void gemm_qkv(
    const unsigned short* __restrict__ A, const unsigned short* __restrict__ Bt,
    unsigned short* __restrict__ qkOut, unsigned short* __restrict__ vtp)
{
    __shared__ unsigned short As[128 * 64];
    __shared__ unsigned short Bs[128 * 64];
    const int tid = threadIdx.x;
    const int w = tid >> 6, lane = tid & 63, quad = lane >> 4, l15 = lane & 15;
    const int wm = w >> 1, wn = w & 1;
    const size_t m0 = (size_t)blockIdx.x * 128, n0 = (size_t)blockIdx.y * 128;
    f32x4 zero = {0.f, 0.f, 0.f, 0.f};
    f32x4 acc[4][4];
    #pragma unroll
    for (int i = 0; i < 4; ++i)
        #pragma unroll
        for (int j = 0; j < 4; ++j) acc[i][j] = zero;

    for (int k0 = 0; k0 < 512; k0 += 64) {
        __syncthreads();
        #pragma unroll
        for (int r = 0; r < 4; ++r) {
            int s = r * 256 + w * 64 + lane;
            int row = s >> 3, x = s & 7, g = x ^ (row & 7);
            async16(A + (m0 + row) * 512 + k0 + g * 8,
                    (char*)As + (size_t)(r * 256 + w * 64) * 16);
        }
        #pragma unroll
        for (int r = 0; r < 4; ++r) {
            int s = r * 256 + w * 64 + lane;
            int row = s >> 3, x = s & 7, g = x ^ (row & 7);
            async16(Bt + (n0 + row) * 512 + k0 + g * 8,
                    (char*)Bs + (size_t)(r * 256 + w * 64) * 16);
        }
        __syncthreads();
        #pragma unroll
        for (int ks = 0; ks < 2; ++ks) {
            bf16x8 af[4], bf[4];
            int cc = ks * 4 + quad;
            #pragma unroll
            for (int mt = 0; mt < 4; ++mt) {
                int row = wm * 64 + mt * 16 + l15;
                int x = cc ^ (row & 7);
                af[mt] = *(const bf16x8*)(As + row * 64 + x * 8);
            }
            #pragma unroll
            for (int nt = 0; nt < 4; ++nt) {
                int row = wn * 64 + nt * 16 + l15;
                int x = cc ^ (row & 7);
                bf[nt] = *(const bf16x8*)(Bs + row * 64 + x * 8);
            }
            #pragma unroll
            for (int mt = 0; mt < 4; ++mt)
                #pragma unroll
                for (int nt = 0; nt < 4; ++nt)
                    acc[mt][nt] = __builtin_amdgcn_mfma_f32_16x16x32_bf16(
                        af[mt], bf[nt], acc[mt][nt], 0, 0, 0);
        }
    }
    if (n0 < 1024) {
        #pragma unroll
        for (int mt = 0; mt < 4; ++mt)
            #pragma unroll
            for (int nt = 0; nt < 4; ++nt)
                #pragma unroll
                for (int r = 0; r < 4; ++r) {
                    size_t grow = m0 + wm * 64 + mt * 16 + quad * 4 + r;
                    size_t gcol = n0 + wn * 64 + nt * 16 + l15;
                    qkOut[grow * 1024 + gcol] = f2bf(acc[mt][nt][r]);
                }
    } else {
        const int b = (int)(m0 >> 12);
        const int tb = (int)(m0 & 4095);
        #pragma unroll
        for (int mt = 0; mt < 4; ++mt)
            #pragma unroll
            for (int nt = 0; nt < 4; ++nt)
                #pragma unroll
                for (int r = 0; r < 4; ++r) {
                    int t = tb + wm * 64 + mt * 16 + quad * 4 + r;
                    int vcol = (int)(n0 - 1024) + wn * 64 + nt * 16 + l15;
                    int jt = t >> 5;
                    int x = (t >> 3) & 3;
                    vtp[(size_t)(b * 128 + jt) * 16384
                        + (size_t)(vcol * 4 + x) * 8 + (t & 7)] =
                        f2bf(acc[mt][nt][r]);
                }
    }
}

// ---------------- GEMM: C[M,N] = A[M,K] * Bt[N,K]^T, bf16 MFMA ----------------
__global__ __launch_bounds__(256) void gemm_bt(
    const unsigned short* __restrict__ A, const unsigned short* __restrict__ Bt,
    void* __restrict__ Cp, int M, int N, int K, int lda, int ldb, int ldc, int outBf16)
{
    __shared__ unsigned short As[128 * 64];
    __shared__ unsigned short Bs[128 * 64];
    const int tid = threadIdx.x;
    const int w = tid >> 6, lane = tid & 63, quad = lane >> 4, l15 = lane & 15;
    const int wm = w >> 1, wn = w & 1;
    const size_t m0 = (size_t)blockIdx.x * 128, n0 = (size_t)blockIdx.y * 128;
    f32x4 zero = {0.f, 0.f, 0.f, 0.f};
    f32x4 acc[4][4];
    #pragma unroll
    for (int i = 0; i < 4; ++i)
        #pragma unroll
        for (int j = 0; j < 4; ++j) acc[i][j] = zero;

    for (int k0 = 0; k0 < K; k0 += 64) {
        __syncthreads();
        #pragma unroll
        for (int r = 0; r < 4; ++r) {
            int s = r * 256 + w * 64 + lane;
            int row = s >> 3, x = s & 7, g = x ^ (row & 7);
            async16(A + (m0 + row) * lda + k0 + g * 8,
                    (char*)As + (size_t)(r * 256 + w * 64) * 16);
        }
        #pragma unroll
        for (int r = 0; r < 4; ++r) {
            int s = r * 256 + w * 64 + lane;
            int row = s >> 3, x = s & 7, g = x ^ (row & 7);
            async16(Bt + (n0 + row) * ldb + k0 + g * 8,
                    (char*)Bs + (size_t)(r * 256 + w * 64) * 16);
        }
        __syncthreads();
        #pragma unroll
        for (int ks = 0; ks < 2; ++ks) {
            bf16x8 af[4], bf[4];
            int cc = ks * 4 + quad;
            #pragma unroll
            for (int mt = 0; mt < 4; ++mt) {
                int row = wm * 64 + mt * 16 + l15;
                int x = cc ^ (row & 7);
                af[mt] = *(const bf16x8*)(As + row * 64 + x * 8);
            }
            #pragma unroll
            for (int nt = 0; nt < 4; ++nt) {
                int row = wn * 64 + nt * 16 + l15;
                int x = cc ^ (row & 7);
                bf[nt] = *(const bf16x8*)(Bs + row * 64 + x * 8);
            }
            #pragma unroll
            for (int mt = 0; mt < 4; ++mt)
                #pragma unroll
                for (int nt = 0; nt < 4; ++nt)
                    acc[mt][nt] = __builtin_amdgcn_mfma_f32_16x16x32_bf16(
                        af[mt], bf[nt], acc[mt][nt], 0, 0, 0);
        }
    }
    #pragma unroll
    for (int mt = 0; mt < 4; ++mt)
        #pragma unroll
        for (int nt = 0; nt < 4; ++nt)
            #pragma unroll
            for (int r = 0; r < 4; ++r) {
                size_t grow = m0 + wm * 64 + mt * 16 + quad * 4 + r;
                size_t gcol = n0 + wn * 64 + nt * 16 + l15;
                float v = acc[mt][nt][r];
                if (outBf16) ((unsigned short*)Cp)[grow * ldc + gcol] = f2bf(v);
                else         ((float*)Cp)[grow * ldc + gcol] = v;
            }
}

// ---------------- Flash attention v19: balanced quarter-jobs, NO atomics ----------------
// v15 loop body (QBLK=64, KVBLK=32, dbuf K, no V staging, d-split PV, setprio).
// Schedule: row-block q's 2q+2 key-tiles split into quarters j=0..3 (each <=32
// tiles). Block i = (a, b, j2) runs quarter j2 of row a, then quarter j2+2 of
// row 63-a: EXACTLY 32-33 tiles per block -> co-resident blocks stay paired to
// the end (v13-v17's solo-tail eliminated; occupancy should rise 12% -> ~22%).
// Each (row, quarter) has ONE writer -> plain bf16 partial stores into ph[j]
// + lp[j] row-sums; empty quarters (q=0 only) fall through and store zeros
// (trip counts block-uniform -> no divergent barriers).
__global__ __launch_bounds__(256, 2) void attn_kernel(
    const unsigned short* __restrict__ qk,    // [b*4096+t][1024] : Q | K
    const unsigned short* __restrict__ vtp,   // UNSWIZZLED panels [b][jt][2048 chunks]
    unsigned short* __restrict__ ph0, unsigned short* __restrict__ ph1,
    unsigned short* __restrict__ ph2, unsigned short* __restrict__ ph3,
    float* __restrict__ lp)                   // [4][16384]
{
    __shared__ unsigned short Ks[2][32 * 512];   // 2x32 KB, source-permuted chunks
    __shared__ unsigned short Ps[64 * 40];       // 5 KB P exchange, stride-40 pad

    const int i = blockIdx.x;
    const int a = i & 63, b = (i >> 6) & 3, j2 = i >> 8;   // j2 in {0,1}

    const int tid = threadIdx.x, w = tid >> 6, lane = tid & 63;
    const int quad = lane >> 4, l15 = lane & 15;
    const float scale = 0.04419417382415922f;  // 1/sqrt(512)
    f32x4 zero = {0.f, 0.f, 0.f, 0.f};

    const unsigned short* kbase = qk + (size_t)(b * 4096) * 1024 + 512;
    const unsigned short* vbase = vtp + (size_t)(b * 128) * 16384;

    const int gE = (lane & ~7) | ((lane ^ w) & 7);
    const int gO = (lane & ~7) | ((lane ^ (w + 4)) & 7);
    const size_t kOffE = (size_t)w * 1024 + (size_t)gE * 8;
    const size_t kOffO = (size_t)(w + 4) * 1024 + (size_t)gO * 8;
    const size_t vLane = (size_t)w * 4096 + (size_t)l15 * 32 + (size_t)quad * 8;

    #define STAGE_K(BUF, T)                                                      \
    {                                                                            \
        const unsigned short* kg = kbase + (size_t)(T) * 32768;                  \
        _Pragma("unroll")                                                        \
        for (int rr = 0; rr < 4; ++rr) {                                         \
            async16(kg + (size_t)(2 * rr) * 4096 + kOffE,                        \
                    (char*)(&Ks[BUF][0]) + (size_t)((2 * rr) * 256 + w * 64) * 16);\
            async16(kg + (size_t)(2 * rr) * 4096 + kOffO,                        \
                    (char*)(&Ks[BUF][0]) + (size_t)((2 * rr + 1) * 256 + w * 64) * 16);\
        }                                                                        \
    }

    #pragma unroll 1
    for (int s = 0; s < 2; ++s) {
        const int q = s ? (63 - a) : a;
        const int j = s ? (j2 + 2) : j2;
        const int T2 = 2 * q + 2;
        const int t0 = (j * T2) >> 2;             // t0 <= T2-1 always (valid tile)
        const int t1 = ((j + 1) * T2) >> 2;

        // Q fragments for this row-block
        bf16x8 qf[16];
        {
            const unsigned short* qb =
                qk + (size_t)(b * 4096 + q * 64 + w * 16 + l15) * 1024;
            #pragma unroll
            for (int ks = 0; ks < 16; ++ks)
                qf[ks] = *(const bf16x8*)(qb + ks * 32 + quad * 8);
        }
        f32x4 o[4][8];
        #pragma unroll
        for (int ii = 0; ii < 4; ++ii)
            #pragma unroll
            for (int d = 0; d < 8; ++d) o[ii][d] = zero;
        float li[4] = {0.f, 0.f, 0.f, 0.f};

        STAGE_K(0, t0);
        __syncthreads();
        int cur = 0;

        #pragma unroll 1
        for (int jt = t0; jt < t1; ++jt) {
            if (jt + 1 < t1) STAGE_K(cur ^ 1, jt + 1);

            f32x4 sa[2];
            sa[0] = zero; sa[1] = zero;
            __builtin_amdgcn_s_setprio(1);
            #pragma unroll
            for (int ks = 0; ks < 16; ++ks) {
                int cc = ks * 4 + quad;
                #pragma unroll
                for (int nt = 0; nt < 2; ++nt) {
                    int jr = nt * 16 + l15;
                    int xg = (cc & ~7) | ((cc ^ jr) & 7);
                    bf16x8 kf = *(const bf16x8*)(&Ks[cur][jr * 512 + xg * 8]);
                    sa[nt] = __builtin_amdgcn_mfma_f32_16x16x32_bf16(
                        qf[ks], kf, sa[nt], 0, 0, 0);
                }
            }
            __builtin_amdgcn_s_setprio(0);
            const int trow = q * 64 + w * 16 + quad * 4;
            #pragma unroll
            for (int r = 0; r < 4; ++r) {
                #pragma unroll
                for (int nt = 0; nt < 2; ++nt) {
                    int col = jt * 32 + nt * 16 + l15;
                    float sv = sa[nt][r] * scale;
                    float pv = __expf(fminf(sv, 60.f));
                    if (col > trow + r) pv = 0.f;
                    li[r] += pv;
                    Ps[(w * 16 + quad * 4 + r) * 40 + nt * 16 + l15] = f2bf(pv);
                }
            }
            asm volatile("s_waitcnt lgkmcnt(0)" ::: "memory");
            __builtin_amdgcn_s_barrier();

            const unsigned short* vt = vbase + (size_t)jt * 16384 + vLane;
            bf16x8 vfr[8];
            #pragma unroll
            for (int ii = 0; ii < 8; ++ii)
                vfr[ii] = *(const bf16x8*)(vt + (size_t)ii * 512);
            __builtin_amdgcn_s_setprio(1);
            #pragma unroll
            for (int qi = 0; qi < 4; ++qi) {
                bf16x8 pa = *(const bf16x8*)(Ps + (qi * 16 + l15) * 40 + quad * 8);
                #pragma unroll
                for (int ii = 0; ii < 8; ++ii)
                    o[qi][ii] = __builtin_amdgcn_mfma_f32_16x16x32_bf16(
                        pa, vfr[ii], o[qi][ii], 0, 0, 0);
            }
            __builtin_amdgcn_s_setprio(0);
            __syncthreads();
            cur ^= 1;
        }

        // epilogue (always; zeros for empty quarters): one writer per (row, j)
        unsigned short* dst = (j == 0) ? ph0 : (j == 1) ? ph1
                            : (j == 2) ? ph2 : ph3;
        #pragma unroll
        for (int r = 0; r < 4; ++r) {
            float t = li[r];
            t += __shfl_xor(t, 1);
            t += __shfl_xor(t, 2);
            t += __shfl_xor(t, 4);
            t += __shfl_xor(t, 8);
            if (l15 == 0)
                lp[j * 16384 + b * 4096 + q * 64 + w * 16 + quad * 4 + r] = t;
        }
        unsigned short* ob = dst + (size_t)(b * 4096 + q * 64) * 512 + w * 128;
        #pragma unroll
        for (int qi = 0; qi < 4; ++qi)
            #pragma unroll
            for (int df = 0; df < 8; ++df)
                #pragma unroll
                for (int r = 0; r < 4; ++r)
                    ob[(size_t)(qi * 16 + quad * 4 + r) * 512 + df * 16 + l15] =
                        f2bf(o[qi][df][r]);
    }
    #undef STAGE_K
}

// -------- combine: att[t][c] = (ph0+ph1+ph2+ph3)/(l0+l1+l2+l3), bf16 out --------
__global__ __launch_bounds__(256) void combine_kernel(
    const unsigned short* __restrict__ ph0, const unsigned short* __restrict__ ph1,
    const unsigned short* __restrict__ ph2, const unsigned short* __restrict__ ph3,
    const float* __restrict__ lp, unsigned short* __restrict__ att)
{
    int t = blockIdx.x * 4 + (threadIdx.x >> 6);
    int lane = threadIdx.x & 63;
    float inv = 1.0f / (lp[t] + lp[16384 + t] + lp[32768 + t] + lp[49152 + t]);
    const ushort4* pa = (const ushort4*)(ph0 + (size_t)t * 512 + lane * 8);
    const ushort4* pb = (const ushort4*)(ph1 + (size_t)t * 512 + lane * 8);
    const ushort4* pc = (const ushort4*)(ph2 + (size_t)t * 512 + lane * 8);
    const ushort4* pd = (const ushort4*)(ph3 + (size_t)t * 512 + lane * 8);
    ushort4* po = (ushort4*)(att + (size_t)t * 512 + lane * 8);
    #pragma unroll
    for (int i = 0; i < 2; ++i) {
        ushort4 a = pa[i], b = pb[i], c = pc[i], d = pd[i];
        po[i] = make_ushort4(
            f2bf((bf2f(a.x) + bf2f(b.x) + bf2f(c.x) + bf2f(d.x)) * inv),
            f2bf((bf2f(a.y) + bf2f(b.y) + bf2f(c.y) + bf2f(d.y)) * inv),
            f2bf((bf2f(a.z) + bf2f(b.z) + bf2f(c.z) + bf2f(d.z)) * inv),
            f2bf((bf2f(a.w) + bf2f(b.w) + bf2f(c.w) + bf2f(d.w)) * inv));
    }
}

extern "C" void kernel_launch(void* const* d_in, const int* in_sizes, int n_in,
                              void* d_out, int out_size, void* d_ws, size_t ws_size,
                              hipStream_t stream)
{
    const float* x     = (const float*)d_in[0];
    // d_in[1] = causal mask (tril ones) — causality applied analytically, not read
    const float* gamma = (const float*)d_in[2];
    const float* beta  = (const float*)d_in[3];
    const float* Wqkv  = (const float*)d_in[4];
    const float* Wproj = (const float*)d_in[5];
    float* out = (float*)d_out;

    char* ws = (char*)d_ws;
    unsigned short* qk     = (unsigned short*)(ws);              // 16384x1024 bf16 (32 MB)
    unsigned short* ph1    = (unsigned short*)(ws + 33554432);   // quarter-1 partial (16 MB)
    unsigned short* vtp    = (unsigned short*)(ws + 50331648);   // packed Vt (16 MB); att later
    unsigned short* xn     = (unsigned short*)(ws + 67108864);   // LN out (16 MB); ph0 later
    unsigned short* wqkvT  = (unsigned short*)(ws + 83886080);   // 1536x512 bf16; lp later
    unsigned short* wprojT = (unsigned short*)(ws + 85458944);   // 512x512 bf16
    unsigned short* ph0    = xn;    // dead after QKV GEMM
    unsigned short* ph2    = (unsigned short*)out;               // d_out dead until final GEMM
    unsigned short* ph3    = (unsigned short*)out + (size_t)8388608;
    float*          lp     = (float*)wqkvT;  // 4x16384 fp32 (dead after gemm_qkv)
    unsigned short* att    = vtp;   // dead after attn

    ln_bf16_kernel<<<4096, 256, 0, stream>>>(x, gamma, beta, xn, 16384);
    transpose_w2<<<dim3(8, 32), 256, 0, stream>>>(Wqkv, Wproj, wqkvT, wprojT);
    // merged QKV projection: Q|K -> qk (ldc 1024), V -> vtp (direct scatter)
    gemm_qkv<<<dim3(128, 12), 256, 0, stream>>>(xn, wqkvT, qk, vtp);
    attn_kernel<<<512, 256, 0, stream>>>(qk, vtp, ph0, ph1, ph2, ph3, lp);
    // combine 4 quarter-partials -> att (in vtp region), then project
    combine_kernel<<<4096, 256, 0, stream>>>(ph0, ph1, ph2, ph3, lp, att);
    gemm_bt<<<dim3(128, 4), 256, 0, stream>>>(att, wprojT, out,
                                              16384, 512, 512, 512, 512, 512, 0);
}

// Round 14
// 397.238 us; speedup vs baseline: 1.2028x; 1.0250x over previous
//
#include <hip/hip_runtime.h>

typedef short bf16x8 __attribute__((ext_vector_type(8)));
typedef float f32x4 __attribute__((ext_vector_type(4)));

#define AS1 __attribute__((address_space(1)))
#define AS3 __attribute__((address_space(3)))

// async global->LDS, 16B per lane. LDS dest is wave-uniform base + lane*16.
__device__ __forceinline__ void async16(const void* g, void* l) {
    __builtin_amdgcn_global_load_lds((AS1 unsigned*)(unsigned long long)g,
                                     (AS3 unsigned*)l, 16, 0, 0);
}

__device__ __forceinline__ unsigned short f2bf(float f) {
    unsigned u = __builtin_bit_cast(unsigned, f);
    u += 0x7fffu + ((u >> 16) & 1u);   // RNE
    return (unsigned short)(u >> 16);
}
__device__ __forceinline__ float bf2f(unsigned short s) {
    unsigned u = ((unsigned)s) << 16;
    return __builtin_bit_cast(float, u);
}

// ---------------- LayerNorm + bf16 cast: one wave per row of 512 ----------------
__global__ __launch_bounds__(256) void ln_bf16_kernel(
    const float* __restrict__ x, const float* __restrict__ gamma,
    const float* __restrict__ beta, unsigned short* __restrict__ xn, int nrows)
{
    int row = blockIdx.x * 4 + (threadIdx.x >> 6);
    int lane = threadIdx.x & 63;
    if (row >= nrows) return;
    const float4* xr = (const float4*)(x + (size_t)row * 512);
    float4 a = xr[lane], b = xr[lane + 64];
    float s = a.x + a.y + a.z + a.w + b.x + b.y + b.z + b.w;
    #pragma unroll
    for (int m = 1; m < 64; m <<= 1) s += __shfl_xor(s, m);
    float mu = s * (1.0f / 512.0f);
    float dx[8] = {a.x - mu, a.y - mu, a.z - mu, a.w - mu,
                   b.x - mu, b.y - mu, b.z - mu, b.w - mu};
    float ss = 0.f;
    #pragma unroll
    for (int i = 0; i < 8; ++i) ss += dx[i] * dx[i];
    #pragma unroll
    for (int m = 1; m < 64; m <<= 1) ss += __shfl_xor(ss, m);
    float rstd = rsqrtf(ss * (1.0f / 512.0f) + 1e-5f);
    const float4* gp = (const float4*)gamma;
    const float4* bp = (const float4*)beta;
    float4 g0 = gp[lane], g1 = gp[lane + 64], b0 = bp[lane], b1 = bp[lane + 64];
    float y[8];
    y[0] = dx[0] * rstd * g0.x + b0.x; y[1] = dx[1] * rstd * g0.y + b0.y;
    y[2] = dx[2] * rstd * g0.z + b0.z; y[3] = dx[3] * rstd * g0.w + b0.w;
    y[4] = dx[4] * rstd * g1.x + b1.x; y[5] = dx[5] * rstd * g1.y + b1.y;
    y[6] = dx[6] * rstd * g1.z + b1.z; y[7] = dx[7] * rstd * g1.w + b1.w;
    ushort4* orow = (ushort4*)(xn + (size_t)row * 512);
    orow[lane]      = make_ushort4(f2bf(y[0]), f2bf(y[1]), f2bf(y[2]), f2bf(y[3]));
    orow[lane + 64] = make_ushort4(f2bf(y[4]), f2bf(y[5]), f2bf(y[6]), f2bf(y[7]));
}

// ---- fp32 [R][C] -> bf16 transposed [C][R], BOTH weights in one launch ----
__global__ __launch_bounds__(256) void transpose_w2(
    const float* __restrict__ wqkv, const float* __restrict__ wproj,
    unsigned short* __restrict__ wqkvT, unsigned short* __restrict__ wprojT)
{
    __shared__ float tile[64][65];
    const int R = 512;
    int by = blockIdx.y;
    const float* in;
    unsigned short* outT;
    int Cd, c0;
    if (by < 24) { in = wqkv;  outT = wqkvT;  Cd = 1536; c0 = by * 64; }
    else         { in = wproj; outT = wprojT; Cd = 512;  c0 = (by - 24) * 64; }
    int r0 = blockIdx.x * 64;
    int lr = threadIdx.x >> 6, lc = threadIdx.x & 63;
    #pragma unroll
    for (int i = 0; i < 16; ++i) {
        int r = i * 4 + lr;
        tile[r][lc] = in[(size_t)(r0 + r) * Cd + c0 + lc];
    }
    __syncthreads();
    #pragma unroll
    for (int i = 0; i < 16; ++i) {
        int r = i * 4 + lr;
        outT[(size_t)(c0 + r) * R + r0 + lc] = f2bf(tile[lc][r]);
    }
}

// -------- merged QKV GEMM: C[16384,1536] = xn[16384,512] * WqkvT[1536,512]^T --------
__global__ __launch_bounds__(256) void gemm_qkv(
    const unsigned short* __restrict__ A, const unsigned short* __restrict__ Bt,
    unsigned short* __restrict__ qkOut, unsigned short* __restrict__ vtp)
{
    __shared__ unsigned short As[128 * 64];
    __shared__ unsigned short Bs[128 * 64];
    const int tid = threadIdx.x;
    const int w = tid >> 6, lane = tid & 63, quad = lane >> 4, l15 = lane & 15;
    const int wm = w >> 1, wn = w & 1;
    const size_t m0 = (size_t)blockIdx.x * 128, n0 = (size_t)blockIdx.y * 128;
    f32x4 zero = {0.f, 0.f, 0.f, 0.f};
    f32x4 acc[4][4];
    #pragma unroll
    for (int i = 0; i < 4; ++i)
        #pragma unroll
        for (int j = 0; j < 4; ++j) acc[i][j] = zero;

    for (int k0 = 0; k0 < 512; k0 += 64) {
        __syncthreads();
        #pragma unroll
        for (int r = 0; r < 4; ++r) {
            int s = r * 256 + w * 64 + lane;
            int row = s >> 3, x = s & 7, g = x ^ (row & 7);
            async16(A + (m0 + row) * 512 + k0 + g * 8,
                    (char*)As + (size_t)(r * 256 + w * 64) * 16);
        }
        #pragma unroll
        for (int r = 0; r < 4; ++r) {
            int s = r * 256 + w * 64 + lane;
            int row = s >> 3, x = s & 7, g = x ^ (row & 7);
            async16(Bt + (n0 + row) * 512 + k0 + g * 8,
                    (char*)Bs + (size_t)(r * 256 + w * 64) * 16);
        }
        __syncthreads();
        #pragma unroll
        for (int ks = 0; ks < 2; ++ks) {
            bf16x8 af[4], bf[4];
            int cc = ks * 4 + quad;
            #pragma unroll
            for (int mt = 0; mt < 4; ++mt) {
                int row = wm * 64 + mt * 16 + l15;
                int x = cc ^ (row & 7);
                af[mt] = *(const bf16x8*)(As + row * 64 + x * 8);
            }
            #pragma unroll
            for (int nt = 0; nt < 4; ++nt) {
                int row = wn * 64 + nt * 16 + l15;
                int x = cc ^ (row & 7);
                bf[nt] = *(const bf16x8*)(Bs + row * 64 + x * 8);
            }
            #pragma unroll
            for (int mt = 0; mt < 4; ++mt)
                #pragma unroll
                for (int nt = 0; nt < 4; ++nt)
                    acc[mt][nt] = __builtin_amdgcn_mfma_f32_16x16x32_bf16(
                        af[mt], bf[nt], acc[mt][nt], 0, 0, 0);
        }
    }
    if (n0 < 1024) {
        #pragma unroll
        for (int mt = 0; mt < 4; ++mt)
            #pragma unroll
            for (int nt = 0; nt < 4; ++nt)
                #pragma unroll
                for (int r = 0; r < 4; ++r) {
                    size_t grow = m0 + wm * 64 + mt * 16 + quad * 4 + r;
                    size_t gcol = n0 + wn * 64 + nt * 16 + l15;
                    qkOut[grow * 1024 + gcol] = f2bf(acc[mt][nt][r]);
                }
    } else {
        const int b = (int)(m0 >> 12);
        const int tb = (int)(m0 & 4095);
        #pragma unroll
        for (int mt = 0; mt < 4; ++mt)
            #pragma unroll
            for (int nt = 0; nt < 4; ++nt)
                #pragma unroll
                for (int r = 0; r < 4; ++r) {
                    int t = tb + wm * 64 + mt * 16 + quad * 4 + r;
                    int vcol = (int)(n0 - 1024) + wn * 64 + nt * 16 + l15;
                    int jt = t >> 5;
                    int x = (t >> 3) & 3;
                    vtp[(size_t)(b * 128 + jt) * 16384
                        + (size_t)(vcol * 4 + x) * 8 + (t & 7)] =
                        f2bf(acc[mt][nt][r]);
                }
    }
}

// ---------------- GEMM: C[M,N] = A[M,K] * Bt[N,K]^T, bf16 MFMA ----------------
__global__ __launch_bounds__(256) void gemm_bt(
    const unsigned short* __restrict__ A, const unsigned short* __restrict__ Bt,
    void* __restrict__ Cp, int M, int N, int K, int lda, int ldb, int ldc, int outBf16)
{
    __shared__ unsigned short As[128 * 64];
    __shared__ unsigned short Bs[128 * 64];
    const int tid = threadIdx.x;
    const int w = tid >> 6, lane = tid & 63, quad = lane >> 4, l15 = lane & 15;
    const int wm = w >> 1, wn = w & 1;
    const size_t m0 = (size_t)blockIdx.x * 128, n0 = (size_t)blockIdx.y * 128;
    f32x4 zero = {0.f, 0.f, 0.f, 0.f};
    f32x4 acc[4][4];
    #pragma unroll
    for (int i = 0; i < 4; ++i)
        #pragma unroll
        for (int j = 0; j < 4; ++j) acc[i][j] = zero;

    for (int k0 = 0; k0 < K; k0 += 64) {
        __syncthreads();
        #pragma unroll
        for (int r = 0; r < 4; ++r) {
            int s = r * 256 + w * 64 + lane;
            int row = s >> 3, x = s & 7, g = x ^ (row & 7);
            async16(A + (m0 + row) * lda + k0 + g * 8,
                    (char*)As + (size_t)(r * 256 + w * 64) * 16);
        }
        #pragma unroll
        for (int r = 0; r < 4; ++r) {
            int s = r * 256 + w * 64 + lane;
            int row = s >> 3, x = s & 7, g = x ^ (row & 7);
            async16(Bt + (n0 + row) * ldb + k0 + g * 8,
                    (char*)Bs + (size_t)(r * 256 + w * 64) * 16);
        }
        __syncthreads();
        #pragma unroll
        for (int ks = 0; ks < 2; ++ks) {
            bf16x8 af[4], bf[4];
            int cc = ks * 4 + quad;
            #pragma unroll
            for (int mt = 0; mt < 4; ++mt) {
                int row = wm * 64 + mt * 16 + l15;
                int x = cc ^ (row & 7);
                af[mt] = *(const bf16x8*)(As + row * 64 + x * 8);
            }
            #pragma unroll
            for (int nt = 0; nt < 4; ++nt) {
                int row = wn * 64 + nt * 16 + l15;
                int x = cc ^ (row & 7);
                bf[nt] = *(const bf16x8*)(Bs + row * 64 + x * 8);
            }
            #pragma unroll
            for (int mt = 0; mt < 4; ++mt)
                #pragma unroll
                for (int nt = 0; nt < 4; ++nt)
                    acc[mt][nt] = __builtin_amdgcn_mfma_f32_16x16x32_bf16(
                        af[mt], bf[nt], acc[mt][nt], 0, 0, 0);
        }
    }
    #pragma unroll
    for (int mt = 0; mt < 4; ++mt)
        #pragma unroll
        for (int nt = 0; nt < 4; ++nt)
            #pragma unroll
            for (int r = 0; r < 4; ++r) {
                size_t grow = m0 + wm * 64 + mt * 16 + quad * 4 + r;
                size_t gcol = n0 + wn * 64 + nt * 16 + l15;
                float v = acc[mt][nt][r];
                if (outBf16) ((unsigned short*)Cp)[grow * ldc + gcol] = f2bf(v);
                else         ((float*)Cp)[grow * ldc + gcol] = v;
            }
}

// ---------------- Flash attention v20: balanced INTERLEAVED classes ----------------
// v19 post-mortem: quarter-RANGES balanced waves (occupancy 12->21.7%) but broke
// the lockstep tile sweep -> K/V re-reads missed L2/LLC (FETCH 78->590 MB),
// kernel went HBM-bound. v20 keeps the balanced pairing but uses INTERLEAVED
// tile classes: block (a,b,j2) runs tiles {jt == j2 (mod 4)} of row a, then
// tiles {jt == j2+2 (mod 4)} of row 63-a. Still 32-33 tiles per block AND all
// classes sweep jt ascending from 0..3 with stride 4 -> at any instant the
// active tile band is ~4 consecutive tiles/batch (~1 MB) -> L2-resident again.
// One writer per (row, class) -> plain bf16 partials ph[j] + lp[j], no atomics.
__global__ __launch_bounds__(256, 2) void attn_kernel(
    const unsigned short* __restrict__ qk,    // [b*4096+t][1024] : Q | K
    const unsigned short* __restrict__ vtp,   // UNSWIZZLED panels [b][jt][2048 chunks]
    unsigned short* __restrict__ ph0, unsigned short* __restrict__ ph1,
    unsigned short* __restrict__ ph2, unsigned short* __restrict__ ph3,
    float* __restrict__ lp)                   // [4][16384]
{
    __shared__ unsigned short Ks[2][32 * 512];   // 2x32 KB, source-permuted chunks
    __shared__ unsigned short Ps[64 * 40];       // 5 KB P exchange, stride-40 pad

    const int i = blockIdx.x;
    const int a = i & 63, b = (i >> 6) & 3, j2 = i >> 8;   // j2 in {0,1}

    const int tid = threadIdx.x, w = tid >> 6, lane = tid & 63;
    const int quad = lane >> 4, l15 = lane & 15;
    const float scale = 0.04419417382415922f;  // 1/sqrt(512)
    f32x4 zero = {0.f, 0.f, 0.f, 0.f};

    const unsigned short* kbase = qk + (size_t)(b * 4096) * 1024 + 512;
    const unsigned short* vbase = vtp + (size_t)(b * 128) * 16384;

    const int gE = (lane & ~7) | ((lane ^ w) & 7);
    const int gO = (lane & ~7) | ((lane ^ (w + 4)) & 7);
    const size_t kOffE = (size_t)w * 1024 + (size_t)gE * 8;
    const size_t kOffO = (size_t)(w + 4) * 1024 + (size_t)gO * 8;
    const size_t vLane = (size_t)w * 4096 + (size_t)l15 * 32 + (size_t)quad * 8;

    #define STAGE_K(BUF, T)                                                      \
    {                                                                            \
        const unsigned short* kg = kbase + (size_t)(T) * 32768;                  \
        _Pragma("unroll")                                                        \
        for (int rr = 0; rr < 4; ++rr) {                                         \
            async16(kg + (size_t)(2 * rr) * 4096 + kOffE,                        \
                    (char*)(&Ks[BUF][0]) + (size_t)((2 * rr) * 256 + w * 64) * 16);\
            async16(kg + (size_t)(2 * rr) * 4096 + kOffO,                        \
                    (char*)(&Ks[BUF][0]) + (size_t)((2 * rr + 1) * 256 + w * 64) * 16);\
        }                                                                        \
    }

    #pragma unroll 1
    for (int s = 0; s < 2; ++s) {
        const int q = s ? (63 - a) : a;
        const int j = s ? (j2 + 2) : j2;          // tile class 0..3
        const int T2 = 2 * q + 2;                 // tiles in this row
        // tiles jt = j, j+4, ... < T2; empty only for q=0, j>=2 (block-uniform)

        // Q fragments for this row-block
        bf16x8 qf[16];
        {
            const unsigned short* qb =
                qk + (size_t)(b * 4096 + q * 64 + w * 16 + l15) * 1024;
            #pragma unroll
            for (int ks = 0; ks < 16; ++ks)
                qf[ks] = *(const bf16x8*)(qb + ks * 32 + quad * 8);
        }
        f32x4 o[4][8];
        #pragma unroll
        for (int ii = 0; ii < 4; ++ii)
            #pragma unroll
            for (int d = 0; d < 8; ++d) o[ii][d] = zero;
        float li[4] = {0.f, 0.f, 0.f, 0.f};

        STAGE_K(0, j);       // j<=3: always a valid K-tile address (harmless if empty)
        __syncthreads();
        int cur = 0;

        #pragma unroll 1
        for (int jt = j; jt < T2; jt += 4) {
            if (jt + 4 < T2) STAGE_K(cur ^ 1, jt + 4);

            f32x4 sa[2];
            sa[0] = zero; sa[1] = zero;
            __builtin_amdgcn_s_setprio(1);
            #pragma unroll
            for (int ks = 0; ks < 16; ++ks) {
                int cc = ks * 4 + quad;
                #pragma unroll
                for (int nt = 0; nt < 2; ++nt) {
                    int jr = nt * 16 + l15;
                    int xg = (cc & ~7) | ((cc ^ jr) & 7);
                    bf16x8 kf = *(const bf16x8*)(&Ks[cur][jr * 512 + xg * 8]);
                    sa[nt] = __builtin_amdgcn_mfma_f32_16x16x32_bf16(
                        qf[ks], kf, sa[nt], 0, 0, 0);
                }
            }
            __builtin_amdgcn_s_setprio(0);
            const int trow = q * 64 + w * 16 + quad * 4;
            #pragma unroll
            for (int r = 0; r < 4; ++r) {
                #pragma unroll
                for (int nt = 0; nt < 2; ++nt) {
                    int col = jt * 32 + nt * 16 + l15;
                    float sv = sa[nt][r] * scale;
                    float pv = __expf(fminf(sv, 60.f));
                    if (col > trow + r) pv = 0.f;
                    li[r] += pv;
                    Ps[(w * 16 + quad * 4 + r) * 40 + nt * 16 + l15] = f2bf(pv);
                }
            }
            asm volatile("s_waitcnt lgkmcnt(0)" ::: "memory");
            __builtin_amdgcn_s_barrier();

            const unsigned short* vt = vbase + (size_t)jt * 16384 + vLane;
            bf16x8 vfr[8];
            #pragma unroll
            for (int ii = 0; ii < 8; ++ii)
                vfr[ii] = *(const bf16x8*)(vt + (size_t)ii * 512);
            __builtin_amdgcn_s_setprio(1);
            #pragma unroll
            for (int qi = 0; qi < 4; ++qi) {
                bf16x8 pa = *(const bf16x8*)(Ps + (qi * 16 + l15) * 40 + quad * 8);
                #pragma unroll
                for (int ii = 0; ii < 8; ++ii)
                    o[qi][ii] = __builtin_amdgcn_mfma_f32_16x16x32_bf16(
                        pa, vfr[ii], o[qi][ii], 0, 0, 0);
            }
            __builtin_amdgcn_s_setprio(0);
            __syncthreads();
            cur ^= 1;
        }

        // epilogue (always; zeros for empty classes): one writer per (row, class)
        unsigned short* dst = (j == 0) ? ph0 : (j == 1) ? ph1
                            : (j == 2) ? ph2 : ph3;
        #pragma unroll
        for (int r = 0; r < 4; ++r) {
            float t = li[r];
            t += __shfl_xor(t, 1);
            t += __shfl_xor(t, 2);
            t += __shfl_xor(t, 4);
            t += __shfl_xor(t, 8);
            if (l15 == 0)
                lp[j * 16384 + b * 4096 + q * 64 + w * 16 + quad * 4 + r] = t;
        }
        unsigned short* ob = dst + (size_t)(b * 4096 + q * 64) * 512 + w * 128;
        #pragma unroll
        for (int qi = 0; qi < 4; ++qi)
            #pragma unroll
            for (int df = 0; df < 8; ++df)
                #pragma unroll
                for (int r = 0; r < 4; ++r)
                    ob[(size_t)(qi * 16 + quad * 4 + r) * 512 + df * 16 + l15] =
                        f2bf(o[qi][df][r]);
    }
    #undef STAGE_K
}

// -------- combine: att[t][c] = (ph0+ph1+ph2+ph3)/(l0+l1+l2+l3), bf16 out --------
__global__ __launch_bounds__(256) void combine_kernel(
    const unsigned short* __restrict__ ph0, const unsigned short* __restrict__ ph1,
    const unsigned short* __restrict__ ph2, const unsigned short* __restrict__ ph3,
    const float* __restrict__ lp, unsigned short* __restrict__ att)
{
    int t = blockIdx.x * 4 + (threadIdx.x >> 6);
    int lane = threadIdx.x & 63;
    float inv = 1.0f / (lp[t] + lp[16384 + t] + lp[32768 + t] + lp[49152 + t]);
    const ushort4* pa = (const ushort4*)(ph0 + (size_t)t * 512 + lane * 8);
    const ushort4* pb = (const ushort4*)(ph1 + (size_t)t * 512 + lane * 8);
    const ushort4* pc = (const ushort4*)(ph2 + (size_t)t * 512 + lane * 8);
    const ushort4* pd = (const ushort4*)(ph3 + (size_t)t * 512 + lane * 8);
    ushort4* po = (ushort4*)(att + (size_t)t * 512 + lane * 8);
    #pragma unroll
    for (int i = 0; i < 2; ++i) {
        ushort4 a = pa[i], b = pb[i], c = pc[i], d = pd[i];
        po[i] = make_ushort4(
            f2bf((bf2f(a.x) + bf2f(b.x) + bf2f(c.x) + bf2f(d.x)) * inv),
            f2bf((bf2f(a.y) + bf2f(b.y) + bf2f(c.y) + bf2f(d.y)) * inv),
            f2bf((bf2f(a.z) + bf2f(b.z) + bf2f(c.z) + bf2f(d.z)) * inv),
            f2bf((bf2f(a.w) + bf2f(b.w) + bf2f(c.w) + bf2f(d.w)) * inv));
    }
}

extern "C" void kernel_launch(void* const* d_in, const int* in_sizes, int n_in,
                              void* d_out, int out_size, void* d_ws, size_t ws_size,
                              hipStream_t stream)
{
    const float* x     = (const float*)d_in[0];
    // d_in[1] = causal mask (tril ones) — causality applied analytically, not read
    const float* gamma = (const float*)d_in[2];
    const float* beta  = (const float*)d_in[3];
    const float* Wqkv  = (const float*)d_in[4];
    const float* Wproj = (const float*)d_in[5];
    float* out = (float*)d_out;

    char* ws = (char*)d_ws;
    unsigned short* qk     = (unsigned short*)(ws);              // 16384x1024 bf16 (32 MB)
    unsigned short* ph1    = (unsigned short*)(ws + 33554432);   // class-1 partial (16 MB)
    unsigned short* vtp    = (unsigned short*)(ws + 50331648);   // packed Vt (16 MB); att later
    unsigned short* xn     = (unsigned short*)(ws + 67108864);   // LN out (16 MB); ph0 later
    unsigned short* wqkvT  = (unsigned short*)(ws + 83886080);   // 1536x512 bf16; lp later
    unsigned short* wprojT = (unsigned short*)(ws + 85458944);   // 512x512 bf16
    unsigned short* ph0    = xn;    // dead after QKV GEMM
    unsigned short* ph2    = (unsigned short*)out;               // d_out dead until final GEMM
    unsigned short* ph3    = (unsigned short*)out + (size_t)8388608;
    float*          lp     = (float*)wqkvT;  // 4x16384 fp32 (dead after gemm_qkv)
    unsigned short* att    = vtp;   // dead after attn

    ln_bf16_kernel<<<4096, 256, 0, stream>>>(x, gamma, beta, xn, 16384);
    transpose_w2<<<dim3(8, 32), 256, 0, stream>>>(Wqkv, Wproj, wqkvT, wprojT);
    // merged QKV projection: Q|K -> qk (ldc 1024), V -> vtp (direct scatter)
    gemm_qkv<<<dim3(128, 12), 256, 0, stream>>>(xn, wqkvT, qk, vtp);
    attn_kernel<<<512, 256, 0, stream>>>(qk, vtp, ph0, ph1, ph2, ph3, lp);
    // combine 4 class-partials -> att (in vtp region), then project
    combine_kernel<<<4096, 256, 0, stream>>>(ph0, ph1, ph2, ph3, lp, att);
    gemm_bt<<<dim3(128, 4), 256, 0, stream>>>(att, wprojT, out,
                                              16384, 512, 512, 512, 512, 512, 0);
}